// Round 4
// baseline (243.741 us; speedup 1.0000x reference)
//
#include <hip/hip_runtime.h>
#include <float.h>
#include <math.h>

#define SEQ 2048
#define NB 4
#define DIM 128
#define DL 16
#define NEGV (-1e9f)
#define TOPK 8

#define QT 128      // q-rows per out block
#define KC 64       // k chunk staged in LDS
#define PSTR 132    // Pt row stride

typedef unsigned long long u64;

__device__ __forceinline__ int lanes_below(u64 m) {
    return __builtin_amdgcn_mbcnt_hi((unsigned)(m >> 32),
           __builtin_amdgcn_mbcnt_lo((unsigned)m, 0));
}

// ---------------------------------------------------------------------------
// Kernel A: q_low/k_low projections + per-key high-rank correction scalar sh.
// ---------------------------------------------------------------------------
__global__ __launch_bounds__(256) void proj_kernel(
    const float* __restrict__ q, const float* __restrict__ k,
    const float* __restrict__ Wql, const float* __restrict__ bql,
    const float* __restrict__ Wkl, const float* __restrict__ bkl,
    const float* __restrict__ Wqh, const float* __restrict__ bqh,
    const float* __restrict__ Wkh, const float* __restrict__ bkh,
    float* __restrict__ q_low, float* __restrict__ k_low,
    float* __restrict__ sh)
{
    __shared__ float Ws[4][DIM * DL];
    __shared__ float rowq[16][DIM];
    __shared__ float rowk[16][DIM];
    int tid = threadIdx.x;
    for (int i = tid; i < DIM * DL; i += 256) {
        Ws[0][i] = Wql[i];
        Ws[1][i] = Wkl[i];
        Ws[2][i] = Wqh[i];
        Ws[3][i] = Wkh[i];
    }
    int r0 = blockIdx.x * 16;
    for (int i = tid; i < 16 * DIM; i += 256) {
        int rr = i >> 7, cc = i & 127;
        rowq[rr][cc] = q[(size_t)(r0 + rr) * DIM + cc];
        rowk[rr][cc] = k[(size_t)(r0 + rr) * DIM + cc];
    }
    __syncthreads();
    int g = tid >> 4;
    int e = tid & 15;
    float aql = 0.f, akl = 0.f, aqh = 0.f, akh = 0.f;
    #pragma unroll 8
    for (int i = 0; i < DIM; ++i) {
        float qv = rowq[g][i], kv = rowk[g][i];
        aql = fmaf(qv, Ws[0][i * DL + e], aql);
        akl = fmaf(kv, Ws[1][i * DL + e], akl);
        aqh = fmaf(qv, Ws[2][i * DL + e], aqh);
        akh = fmaf(kv, Ws[3][i * DL + e], akh);
    }
    int t = r0 + g;
    q_low[(size_t)t * DL + e] = aql + bql[e];
    k_low[(size_t)t * DL + e] = akl + bkl[e];
    float qp = aqh + bqh[e];
    float kp = akh + bkh[e];
    float prod = qp * kp;
    #pragma unroll
    for (int off = 8; off >= 1; off >>= 1)
        prod += __shfl_xor(prod, off, 16);
    if (e == 0) sh[t] = 0.25f * prod;
}

// ---------------------------------------------------------------------------
// Kernel B v4: one WAVE per row. Scores in regs; value-only top-8 (max/min
// insert, 16 inst/col), f32 butterfly merge -> t8. Fast path: exactly 8
// elements >= t8 -> predicate selects them; write sh for winners, score
// otherwise (fused scatter). Tie path (c_ge>8): ballot+mbcnt ordinal picks
// the (8 - c_gt) smallest-index ties — exact lax.top_k semantics.
// ---------------------------------------------------------------------------
__global__ __launch_bounds__(256) void score_topk4(
    const float* __restrict__ q_low, const float* __restrict__ k_low,
    const float* __restrict__ sh, const int* __restrict__ valid_lens,
    float* __restrict__ Smat)
{
    int lane = threadIdx.x & 63;
    int wv   = threadIdx.x >> 6;
    int row  = __builtin_amdgcn_readfirstlane(blockIdx.x * 4 + wv); // 0..8191
    int b    = row >> 11;
    int qi   = row & (SEQ - 1);

    const float* qp = q_low + (size_t)row * DL;
    float qv[16];
    #pragma unroll
    for (int e = 0; e < 16; ++e) qv[e] = qp[e];

    const float* kb = k_low + (size_t)b * SEQ * DL;
    const int*   vl = valid_lens + (size_t)b * SEQ;
    const float* shb = sh + (size_t)b * SEQ;
    float* Srow = Smat + (size_t)row * SEQ;

    float sc[32];
    float s[8];
    #pragma unroll
    for (int i = 0; i < 8; ++i) s[i] = -FLT_MAX;

    #pragma unroll 2
    for (int j = 0; j < 32; ++j) {
        int col = lane + j * 64;
        const float4* kp4 = (const float4*)(kb + (size_t)col * DL);
        float4 v0 = kp4[0], v1 = kp4[1], v2 = kp4[2], v3 = kp4[3];
        float acc = 0.f;
        acc = fmaf(qv[0],  v0.x, acc); acc = fmaf(qv[1],  v0.y, acc);
        acc = fmaf(qv[2],  v0.z, acc); acc = fmaf(qv[3],  v0.w, acc);
        acc = fmaf(qv[4],  v1.x, acc); acc = fmaf(qv[5],  v1.y, acc);
        acc = fmaf(qv[6],  v1.z, acc); acc = fmaf(qv[7],  v1.w, acc);
        acc = fmaf(qv[8],  v2.x, acc); acc = fmaf(qv[9],  v2.y, acc);
        acc = fmaf(qv[10], v2.z, acc); acc = fmaf(qv[11], v2.w, acc);
        acc = fmaf(qv[12], v3.x, acc); acc = fmaf(qv[13], v3.y, acc);
        acc = fmaf(qv[14], v3.z, acc); acc = fmaf(qv[15], v3.w, acc);
        acc *= 0.25f;
        int vli = vl[col];
        vli = vli < 0 ? 0 : (vli > SEQ - 1 ? SEQ - 1 : vli);
        if (vli == qi) acc += NEGV;
        sc[j] = acc;

        float key = acc;
        #pragma unroll
        for (int i = 0; i < 8; ++i) {
            float a = s[i];
            s[i] = fmaxf(a, key);
            key  = fminf(a, key);
        }
    }

    // f32 butterfly merge across 64 lanes (max-split + bitonic clean 4,2,1)
    #pragma unroll
    for (int off = 1; off < 64; off <<= 1) {
        float o[8], t[8];
        #pragma unroll
        for (int i = 0; i < 8; ++i)
            o[i] = __shfl_xor(s[i], off, 64);
        #pragma unroll
        for (int i = 0; i < 8; ++i)
            t[i] = fmaxf(s[i], o[7 - i]);
        #pragma unroll
        for (int i = 0; i < 4; ++i) {
            float a = t[i], c = t[i + 4];
            t[i] = fmaxf(a, c); t[i + 4] = fminf(a, c);
        }
        #pragma unroll
        for (int g2 = 0; g2 < 8; g2 += 4) {
            float a = t[g2], c = t[g2 + 2];
            t[g2] = fmaxf(a, c); t[g2 + 2] = fminf(a, c);
            a = t[g2 + 1]; c = t[g2 + 3];
            t[g2 + 1] = fmaxf(a, c); t[g2 + 3] = fminf(a, c);
        }
        #pragma unroll
        for (int g1 = 0; g1 < 8; g1 += 2) {
            float a = t[g1], c = t[g1 + 1];
            t[g1] = fmaxf(a, c); t[g1 + 1] = fminf(a, c);
        }
        #pragma unroll
        for (int i = 0; i < 8; ++i) s[i] = t[i];
    }
    float t8 = s[7];

    // counts (packed: gt in hi16, ge in lo16; sums < 65536)
    int cnt = 0;
    #pragma unroll
    for (int j = 0; j < 32; ++j) {
        cnt += (sc[j] >= t8) ? 1 : 0;
        cnt += (sc[j] >  t8) ? 65536 : 0;
    }
    #pragma unroll
    for (int off = 1; off < 64; off <<= 1)
        cnt += __shfl_xor(cnt, off, 64);
    int c_ge = cnt & 0xFFFF;
    int c_gt = cnt >> 16;

    if (c_ge == 8) {
        #pragma unroll 4
        for (int j = 0; j < 32; ++j) {
            int col = lane + j * 64;
            float v = sc[j];
            if (v >= t8) v = shb[col];
            Srow[col] = v;
        }
    } else {
        int need = 8 - c_gt;
        int total = 0;
        for (int j = 0; j < 32; ++j) {
            int col = lane + j * 64;
            bool eq = (sc[j] == t8);
            u64 bal = __ballot(eq);
            int before = total + lanes_below(bal);
            bool sel = (sc[j] > t8) || (eq && before < need);
            float v = sc[j];
            if (sel) v = shb[col];
            Srow[col] = v;
            total += (int)__popcll(bal);
        }
    }
}

// ---------------------------------------------------------------------------
// Kernel C1: per-column (over q) online softmax partials, q chunked by 128.
// ---------------------------------------------------------------------------
__global__ __launch_bounds__(256) void colred_partial(
    const float* __restrict__ Smat, float* __restrict__ pm, float* __restrict__ pl)
{
    int kcol = blockIdx.x * 256 + threadIdx.x;
    int qc = blockIdx.y;
    int b  = blockIdx.z;
    const float* Sp = Smat + (size_t)b * SEQ * SEQ + (size_t)(qc * 128) * SEQ + kcol;
    float m = -FLT_MAX, l = 0.f;
    for (int qq = 0; qq < 128; ++qq) {
        float v = Sp[(size_t)qq * SEQ];
        float nm = fmaxf(m, v);
        l = l * __expf(m - nm) + __expf(v - nm);
        m = nm;
    }
    pm[((size_t)b * 16 + qc) * SEQ + kcol] = m;
    pl[((size_t)b * 16 + qc) * SEQ + kcol] = l;
}

__global__ __launch_bounds__(256) void colred_final(
    const float* __restrict__ pm, const float* __restrict__ pl,
    float* __restrict__ cmax, float* __restrict__ cinv)
{
    int idx = blockIdx.x * 256 + threadIdx.x;
    int b = idx >> 11, kcol = idx & (SEQ - 1);
    float m = -FLT_MAX, l = 0.f;
    #pragma unroll
    for (int c = 0; c < 16; ++c) {
        float mm = pm[((size_t)b * 16 + c) * SEQ + kcol];
        float ll = pl[((size_t)b * 16 + c) * SEQ + kcol];
        float nm = fmaxf(m, mm);
        l = l * __expf(m - nm) + ll * __expf(mm - nm);
        m = nm;
    }
    cmax[idx] = m;
    cinv[idx] = 1.f / l;
}

// ---------------------------------------------------------------------------
// Kernel D v2: partial out over a k-range. QT=128 q-rows per block, 8x8
// register tile per thread, P staged transposed.
// ---------------------------------------------------------------------------
__global__ __launch_bounds__(256, 2) void out_kernel2(
    const float* __restrict__ Smat, const float* __restrict__ values,
    const float* __restrict__ cmax, const float* __restrict__ cinv,
    float* __restrict__ dst, int krange)
{
    __shared__ float Vt[KC * DIM];
    __shared__ float Pt[KC * PSTR];

    int tid = threadIdx.x;
    int q0 = blockIdx.x * QT;
    int ks = blockIdx.y;
    int b  = blockIdx.z;
    int kbeg = ks * krange;

    int tx = tid & 15;
    int ty = tid >> 4;
    int c0 = tx * 8;
    int r0 = ty * 8;

    float acc[8][8];
    #pragma unroll
    for (int i = 0; i < 8; ++i)
        #pragma unroll
        for (int j = 0; j < 8; ++j) acc[i][j] = 0.f;

    const float* Sb = Smat + (size_t)b * SEQ * SEQ;
    const float* Vb = values + (size_t)b * SEQ * DIM;
    const float* cm = cmax + (size_t)b * SEQ;
    const float* ci = cinv + (size_t)b * SEQ;

    for (int k0 = kbeg; k0 < kbeg + krange; k0 += KC) {
        const float4* Vg4 = (const float4*)(Vb + (size_t)k0 * DIM);
        float4* Vt4 = (float4*)Vt;
        #pragma unroll
        for (int v = 0; v < 8; ++v)
            Vt4[tid + v * 256] = Vg4[tid + v * 256];
        {
            int kk4 = (tid & 15) * 4;
            int qrow0 = tid >> 4;
            float4 cmv = *(const float4*)(cm + k0 + kk4);
            float4 civ = *(const float4*)(ci + k0 + kk4);
            #pragma unroll
            for (int it = 0; it < 8; ++it) {
                int qq = qrow0 + it * 16;
                float4 s = *(const float4*)(Sb + (size_t)(q0 + qq) * SEQ + k0 + kk4);
                Pt[(kk4 + 0) * PSTR + qq] = __expf(s.x - cmv.x) * civ.x;
                Pt[(kk4 + 1) * PSTR + qq] = __expf(s.y - cmv.y) * civ.y;
                Pt[(kk4 + 2) * PSTR + qq] = __expf(s.z - cmv.z) * civ.z;
                Pt[(kk4 + 3) * PSTR + qq] = __expf(s.w - cmv.w) * civ.w;
            }
        }
        __syncthreads();
        #pragma unroll 2
        for (int kk = 0; kk < KC; ++kk) {
            float4 pa = *(const float4*)&Pt[kk * PSTR + r0];
            float4 pb = *(const float4*)&Pt[kk * PSTR + r0 + 4];
            float4 va = *(const float4*)&Vt[kk * DIM + c0];
            float4 vb = *(const float4*)&Vt[kk * DIM + c0 + 4];
            float p[8] = {pa.x, pa.y, pa.z, pa.w, pb.x, pb.y, pb.z, pb.w};
            float v[8] = {va.x, va.y, va.z, va.w, vb.x, vb.y, vb.z, vb.w};
            #pragma unroll
            for (int i = 0; i < 8; ++i)
                #pragma unroll
                for (int j = 0; j < 8; ++j)
                    acc[i][j] = fmaf(p[i], v[j], acc[i][j]);
        }
        __syncthreads();
    }

    float* dp = dst + (size_t)ks * ((size_t)NB * SEQ * DIM) + (size_t)b * SEQ * DIM;
    #pragma unroll
    for (int i = 0; i < 8; ++i) {
        float* o = dp + (size_t)(q0 + r0 + i) * DIM + c0;
        *(float4*)(o)     = make_float4(acc[i][0], acc[i][1], acc[i][2], acc[i][3]);
        *(float4*)(o + 4) = make_float4(acc[i][4], acc[i][5], acc[i][6], acc[i][7]);
    }
}

__global__ __launch_bounds__(256) void reduce_kernel(
    const float* __restrict__ part, float* __restrict__ out, int ksplit)
{
    int idx = blockIdx.x * 256 + threadIdx.x;
    const float4* p = (const float4*)part;
    float4 a = p[idx];
    for (int s = 1; s < ksplit; ++s) {
        float4 q = p[(size_t)idx + (size_t)s * 262144];
        a.x += q.x; a.y += q.y; a.z += q.z; a.w += q.w;
    }
    ((float4*)out)[idx] = a;
}

extern "C" void kernel_launch(void* const* d_in, const int* in_sizes, int n_in,
                              void* d_out, int out_size, void* d_ws, size_t ws_size,
                              hipStream_t stream)
{
    const float* queries = (const float*)d_in[0];
    const float* keys    = (const float*)d_in[1];
    const float* values  = (const float*)d_in[2];
    const int*   valid   = (const int*)d_in[3];
    const float* Wql = (const float*)d_in[4];
    const float* bql = (const float*)d_in[5];
    const float* Wkl = (const float*)d_in[6];
    const float* bkl = (const float*)d_in[7];
    const float* Wqh = (const float*)d_in[8];
    const float* bqh = (const float*)d_in[9];
    const float* Wkh = (const float*)d_in[10];
    const float* bkh = (const float*)d_in[11];

    char* ws = (char*)d_ws;
    float* Smat  = (float*)(ws);                       // 64 MB
    float* q_low = (float*)(ws + 67108864);            // 512 KB
    float* k_low = (float*)(ws + 67108864 + 524288);   // 512 KB
    float* sh    = (float*)(ws + 67108864 + 1048576);  // 32 KB
    float* pm    = (float*)(ws + 67108864 + 1081344);  // 512 KB
    float* pl    = (float*)(ws + 67108864 + 1605632);  // 512 KB
    float* cmax  = (float*)(ws + 67108864 + 2129920);  // 32 KB
    float* cinv  = (float*)(ws + 67108864 + 2162688);  // 32 KB

    const size_t part_off = 73400320;                  // 70 MiB
    const size_t part_sz  = (size_t)NB * SEQ * DIM * 4;
    int ksplit = 1;
    if      (ws_size >= part_off + 8 * part_sz) ksplit = 8;
    else if (ws_size >= part_off + 4 * part_sz) ksplit = 4;
    else if (ws_size >= part_off + 2 * part_sz) ksplit = 2;
    float* part = (float*)(ws + part_off);

    proj_kernel<<<dim3((NB * SEQ) / 16), 256, 0, stream>>>(
        queries, keys, Wql, bql, Wkl, bkl, Wqh, bqh, Wkh, bkh, q_low, k_low, sh);

    score_topk4<<<dim3((NB * SEQ) / 4), 256, 0, stream>>>(
        q_low, k_low, sh, valid, Smat);

    colred_partial<<<dim3(SEQ / 256, 16, NB), 256, 0, stream>>>(Smat, pm, pl);

    colred_final<<<dim3((NB * SEQ) / 256), 256, 0, stream>>>(pm, pl, cmax, cinv);

    if (ksplit == 1) {
        out_kernel2<<<dim3(SEQ / QT, 1, NB), 256, 0, stream>>>(
            Smat, values, cmax, cinv, (float*)d_out, SEQ);
    } else {
        out_kernel2<<<dim3(SEQ / QT, ksplit, NB), 256, 0, stream>>>(
            Smat, values, cmax, cinv, part, SEQ / ksplit);
        reduce_kernel<<<(NB * SEQ * DIM / 4) / 256, 256, 0, stream>>>(
            part, (float*)d_out, ksplit);
    }
}

// Round 5
// 221.653 us; speedup vs baseline: 1.0997x; 1.0997x over previous
//
#include <hip/hip_runtime.h>
#include <float.h>
#include <math.h>

#define SEQ 2048
#define NB 4
#define DIM 128
#define DL 16
#define NEGV (-1e9f)
#define TOPK 8

#define QT 128      // q-rows per out block
#define KC 64       // k chunk staged in LDS (out kernel)
#define PSTR 132    // Pt row stride
#define QCH 64      // q-chunk for colred

typedef unsigned long long u64;

__device__ __forceinline__ int lanes_below(u64 m) {
    return __builtin_amdgcn_mbcnt_hi((unsigned)(m >> 32),
           __builtin_amdgcn_mbcnt_lo((unsigned)m, 0));
}

__device__ __forceinline__ void top8_insert(float* s, float key) {
    #pragma unroll
    for (int i = 0; i < 8; ++i) {
        float a = s[i];
        s[i] = fmaxf(a, key);
        key  = fminf(a, key);
    }
}

// butterfly merge of per-lane sorted-8 (desc) across 64 lanes; returns 8th max
__device__ __forceinline__ float top8_merge(float* s) {
    #pragma unroll
    for (int off = 1; off < 64; off <<= 1) {
        float o[8], t[8];
        #pragma unroll
        for (int i = 0; i < 8; ++i)
            o[i] = __shfl_xor(s[i], off, 64);
        #pragma unroll
        for (int i = 0; i < 8; ++i)
            t[i] = fmaxf(s[i], o[7 - i]);
        #pragma unroll
        for (int i = 0; i < 4; ++i) {
            float a = t[i], c = t[i + 4];
            t[i] = fmaxf(a, c); t[i + 4] = fminf(a, c);
        }
        #pragma unroll
        for (int g2 = 0; g2 < 8; g2 += 4) {
            float a = t[g2], c = t[g2 + 2];
            t[g2] = fmaxf(a, c); t[g2 + 2] = fminf(a, c);
            a = t[g2 + 1]; c = t[g2 + 3];
            t[g2 + 1] = fmaxf(a, c); t[g2 + 3] = fminf(a, c);
        }
        #pragma unroll
        for (int g1 = 0; g1 < 8; g1 += 2) {
            float a = t[g1], c = t[g1 + 1];
            t[g1] = fmaxf(a, c); t[g1 + 1] = fminf(a, c);
        }
        #pragma unroll
        for (int i = 0; i < 8; ++i) s[i] = t[i];
    }
    return s[7];
}

// ---------------------------------------------------------------------------
// Kernel A: q_low/k_low projections + per-key high-rank correction scalar sh.
// ---------------------------------------------------------------------------
__global__ __launch_bounds__(256) void proj_kernel(
    const float* __restrict__ q, const float* __restrict__ k,
    const float* __restrict__ Wql, const float* __restrict__ bql,
    const float* __restrict__ Wkl, const float* __restrict__ bkl,
    const float* __restrict__ Wqh, const float* __restrict__ bqh,
    const float* __restrict__ Wkh, const float* __restrict__ bkh,
    float* __restrict__ q_low, float* __restrict__ k_low,
    float* __restrict__ sh)
{
    __shared__ float Ws[4][DIM * DL];
    __shared__ float rowq[16][DIM];
    __shared__ float rowk[16][DIM];
    int tid = threadIdx.x;
    for (int i = tid; i < DIM * DL; i += 256) {
        Ws[0][i] = Wql[i];
        Ws[1][i] = Wkl[i];
        Ws[2][i] = Wqh[i];
        Ws[3][i] = Wkh[i];
    }
    int r0 = blockIdx.x * 16;
    for (int i = tid; i < 16 * DIM; i += 256) {
        int rr = i >> 7, cc = i & 127;
        rowq[rr][cc] = q[(size_t)(r0 + rr) * DIM + cc];
        rowk[rr][cc] = k[(size_t)(r0 + rr) * DIM + cc];
    }
    __syncthreads();
    int g = tid >> 4;
    int e = tid & 15;
    float aql = 0.f, akl = 0.f, aqh = 0.f, akh = 0.f;
    #pragma unroll 8
    for (int i = 0; i < DIM; ++i) {
        float qv = rowq[g][i], kv = rowk[g][i];
        aql = fmaf(qv, Ws[0][i * DL + e], aql);
        akl = fmaf(kv, Ws[1][i * DL + e], akl);
        aqh = fmaf(qv, Ws[2][i * DL + e], aqh);
        akh = fmaf(kv, Ws[3][i * DL + e], akh);
    }
    int t = r0 + g;
    q_low[(size_t)t * DL + e] = aql + bql[e];
    k_low[(size_t)t * DL + e] = akl + bkl[e];
    float qp = aqh + bqh[e];
    float kp = akh + bkh[e];
    float prod = qp * kp;
    #pragma unroll
    for (int off = 8; off >= 1; off >>= 1)
        prod += __shfl_xor(prod, off, 16);
    if (e == 0) sh[t] = 0.25f * prod;
}

// ---------------------------------------------------------------------------
// Kernel B v5: block = 4 waves x 2 rows = 8 rows (same batch). k_low staged
// per block in 256-col chunks through 2-buffer LDS pipeline (reg prefetch ->
// ds_write -> 1 barrier). Pass 1: scores -> Smat + value-only top-8. Pass 2:
// re-read row from L2, count >= t8, patch only the 8 winners with sh
// (exact tie ordinal via ballot+mbcnt, lax.top_k semantics).
// ---------------------------------------------------------------------------
__global__ __launch_bounds__(256) void score_topk5(
    const float* __restrict__ q_low, const float* __restrict__ k_low,
    const float* __restrict__ sh, const int* __restrict__ valid_lens,
    float* __restrict__ Smat)
{
    __shared__ float KT[2][256 * DL];   // 2 x 16 KB

    int tid  = threadIdx.x;
    int lane = tid & 63;
    int wv   = tid >> 6;
    int row0 = __builtin_amdgcn_readfirstlane(blockIdx.x * 8 + wv * 2);
    int b    = row0 >> 11;
    int qi0  = row0 & (SEQ - 1);
    int qi1  = qi0 + 1;

    float qv0[16], qv1[16];
    {
        const float* qp0 = q_low + (size_t)row0 * DL;
        #pragma unroll
        for (int e = 0; e < 16; ++e) { qv0[e] = qp0[e]; qv1[e] = qp0[DL + e]; }
    }

    const float4* kb4 = (const float4*)(k_low + (size_t)b * SEQ * DL);
    const int*    vlb = valid_lens + (size_t)b * SEQ;
    const float*  shb = sh + (size_t)b * SEQ;
    float* Srow0 = Smat + (size_t)row0 * SEQ;
    float* Srow1 = Srow0 + SEQ;

    float s0[8], s1[8];
    #pragma unroll
    for (int i = 0; i < 8; ++i) { s0[i] = -FLT_MAX; s1[i] = -FLT_MAX; }

    // prologue: stage chunk 0
    float4 stg[4];
    #pragma unroll
    for (int i = 0; i < 4; ++i) stg[i] = kb4[tid + i * 256];
    {
        float4* d = (float4*)KT[0];
        #pragma unroll
        for (int i = 0; i < 4; ++i) d[tid + i * 256] = stg[i];
    }
    __syncthreads();

    for (int c = 0; c < 8; ++c) {
        if (c < 7) {
            #pragma unroll
            for (int i = 0; i < 4; ++i)
                stg[i] = kb4[(c + 1) * 1024 + tid + i * 256];
        }
        // prefetch vl for my 4 cols
        int vli[4];
        #pragma unroll
        for (int j = 0; j < 4; ++j)
            vli[j] = vlb[c * 256 + lane + j * 64];

        const float* Kc = KT[c & 1];
        #pragma unroll
        for (int j = 0; j < 4; ++j) {
            int ccol = lane + j * 64;
            int col  = c * 256 + ccol;
            const float4* kp4 = (const float4*)(Kc + ccol * DL);
            float4 v0 = kp4[0], v1 = kp4[1], v2 = kp4[2], v3 = kp4[3];

            float a0 = 0.f, a1 = 0.f;
            a0 = fmaf(qv0[0],  v0.x, a0); a1 = fmaf(qv1[0],  v0.x, a1);
            a0 = fmaf(qv0[1],  v0.y, a0); a1 = fmaf(qv1[1],  v0.y, a1);
            a0 = fmaf(qv0[2],  v0.z, a0); a1 = fmaf(qv1[2],  v0.z, a1);
            a0 = fmaf(qv0[3],  v0.w, a0); a1 = fmaf(qv1[3],  v0.w, a1);
            a0 = fmaf(qv0[4],  v1.x, a0); a1 = fmaf(qv1[4],  v1.x, a1);
            a0 = fmaf(qv0[5],  v1.y, a0); a1 = fmaf(qv1[5],  v1.y, a1);
            a0 = fmaf(qv0[6],  v1.z, a0); a1 = fmaf(qv1[6],  v1.z, a1);
            a0 = fmaf(qv0[7],  v1.w, a0); a1 = fmaf(qv1[7],  v1.w, a1);
            a0 = fmaf(qv0[8],  v2.x, a0); a1 = fmaf(qv1[8],  v2.x, a1);
            a0 = fmaf(qv0[9],  v2.y, a0); a1 = fmaf(qv1[9],  v2.y, a1);
            a0 = fmaf(qv0[10], v2.z, a0); a1 = fmaf(qv1[10], v2.z, a1);
            a0 = fmaf(qv0[11], v2.w, a0); a1 = fmaf(qv1[11], v2.w, a1);
            a0 = fmaf(qv0[12], v3.x, a0); a1 = fmaf(qv1[12], v3.x, a1);
            a0 = fmaf(qv0[13], v3.y, a0); a1 = fmaf(qv1[13], v3.y, a1);
            a0 = fmaf(qv0[14], v3.z, a0); a1 = fmaf(qv1[14], v3.z, a1);
            a0 = fmaf(qv0[15], v3.w, a0); a1 = fmaf(qv1[15], v3.w, a1);
            a0 *= 0.25f; a1 *= 0.25f;

            int v = vli[j];
            v = v < 0 ? 0 : (v > SEQ - 1 ? SEQ - 1 : v);
            if (v == qi0) a0 += NEGV;
            if (v == qi1) a1 += NEGV;
            Srow0[col] = a0;
            Srow1[col] = a1;
            top8_insert(s0, a0);
            top8_insert(s1, a1);
        }
        if (c < 7) {
            float4* d = (float4*)KT[(c + 1) & 1];
            #pragma unroll
            for (int i = 0; i < 4; ++i) d[tid + i * 256] = stg[i];
            __syncthreads();
        }
    }

    float t8[2];
    t8[0] = top8_merge(s0);
    t8[1] = top8_merge(s1);

    // pass 2: per row, count and patch winners only
    for (int r = 0; r < 2; ++r) {
        float* Sr = r ? Srow1 : Srow0;
        float thr = t8[r];
        float sc[32];
        #pragma unroll 8
        for (int j = 0; j < 32; ++j)
            sc[j] = Sr[lane + j * 64];
        int cnt = 0;
        #pragma unroll
        for (int j = 0; j < 32; ++j) {
            cnt += (sc[j] >= thr) ? 1 : 0;
            cnt += (sc[j] >  thr) ? 65536 : 0;
        }
        #pragma unroll
        for (int off = 1; off < 64; off <<= 1)
            cnt += __shfl_xor(cnt, off, 64);
        int c_ge = cnt & 0xFFFF;
        int c_gt = cnt >> 16;

        if (c_ge == 8) {
            #pragma unroll 8
            for (int j = 0; j < 32; ++j) {
                int col = lane + j * 64;
                if (sc[j] >= thr) Sr[col] = shb[col];
            }
        } else {
            int need = 8 - c_gt;
            int total = 0;
            for (int j = 0; j < 32; ++j) {
                int col = lane + j * 64;
                bool eq = (sc[j] == thr);
                u64 bal = __ballot(eq);
                int before = total + lanes_below(bal);
                bool sel = (sc[j] > thr) || (eq && before < need);
                if (sel) Sr[col] = shb[col];
                total += (int)__popcll(bal);
            }
        }
    }
}

// ---------------------------------------------------------------------------
// Kernel C1: per-column (over q) online softmax partials, q chunked by QCH.
// ---------------------------------------------------------------------------
__global__ __launch_bounds__(256) void colred_partial(
    const float* __restrict__ Smat, float* __restrict__ pm, float* __restrict__ pl)
{
    int kcol = blockIdx.x * 256 + threadIdx.x;
    int qc = blockIdx.y;   // 0..31
    int b  = blockIdx.z;
    const float* Sp = Smat + (size_t)b * SEQ * SEQ + (size_t)(qc * QCH) * SEQ + kcol;
    float m = -FLT_MAX, l = 0.f;
    #pragma unroll 4
    for (int qq = 0; qq < QCH; ++qq) {
        float v = Sp[(size_t)qq * SEQ];
        float nm = fmaxf(m, v);
        l = l * __expf(m - nm) + __expf(v - nm);
        m = nm;
    }
    pm[((size_t)b * 32 + qc) * SEQ + kcol] = m;
    pl[((size_t)b * 32 + qc) * SEQ + kcol] = l;
}

__global__ __launch_bounds__(256) void colred_final(
    const float* __restrict__ pm, const float* __restrict__ pl,
    float* __restrict__ cmax, float* __restrict__ cinv)
{
    int idx = blockIdx.x * 256 + threadIdx.x;
    int b = idx >> 11, kcol = idx & (SEQ - 1);
    float m = -FLT_MAX, l = 0.f;
    #pragma unroll
    for (int c = 0; c < 32; ++c) {
        float mm = pm[((size_t)b * 32 + c) * SEQ + kcol];
        float ll = pl[((size_t)b * 32 + c) * SEQ + kcol];
        float nm = fmaxf(m, mm);
        l = l * __expf(m - nm) + ll * __expf(mm - nm);
        m = nm;
    }
    cmax[idx] = m;
    cinv[idx] = 1.f / l;
}

// ---------------------------------------------------------------------------
// Kernel D v2: partial out over a k-range. QT=128 q-rows per block, 8x8
// register tile per thread, P staged transposed.
// ---------------------------------------------------------------------------
__global__ __launch_bounds__(256, 2) void out_kernel2(
    const float* __restrict__ Smat, const float* __restrict__ values,
    const float* __restrict__ cmax, const float* __restrict__ cinv,
    float* __restrict__ dst, int krange)
{
    __shared__ float Vt[KC * DIM];
    __shared__ float Pt[KC * PSTR];

    int tid = threadIdx.x;
    int q0 = blockIdx.x * QT;
    int ks = blockIdx.y;
    int b  = blockIdx.z;
    int kbeg = ks * krange;

    int tx = tid & 15;
    int ty = tid >> 4;
    int c0 = tx * 8;
    int r0 = ty * 8;

    float acc[8][8];
    #pragma unroll
    for (int i = 0; i < 8; ++i)
        #pragma unroll
        for (int j = 0; j < 8; ++j) acc[i][j] = 0.f;

    const float* Sb = Smat + (size_t)b * SEQ * SEQ;
    const float* Vb = values + (size_t)b * SEQ * DIM;
    const float* cm = cmax + (size_t)b * SEQ;
    const float* ci = cinv + (size_t)b * SEQ;

    for (int k0 = kbeg; k0 < kbeg + krange; k0 += KC) {
        const float4* Vg4 = (const float4*)(Vb + (size_t)k0 * DIM);
        float4* Vt4 = (float4*)Vt;
        #pragma unroll
        for (int v = 0; v < 8; ++v)
            Vt4[tid + v * 256] = Vg4[tid + v * 256];
        {
            int kk4 = (tid & 15) * 4;
            int qrow0 = tid >> 4;
            float4 cmv = *(const float4*)(cm + k0 + kk4);
            float4 civ = *(const float4*)(ci + k0 + kk4);
            #pragma unroll
            for (int it = 0; it < 8; ++it) {
                int qq = qrow0 + it * 16;
                float4 s = *(const float4*)(Sb + (size_t)(q0 + qq) * SEQ + k0 + kk4);
                Pt[(kk4 + 0) * PSTR + qq] = __expf(s.x - cmv.x) * civ.x;
                Pt[(kk4 + 1) * PSTR + qq] = __expf(s.y - cmv.y) * civ.y;
                Pt[(kk4 + 2) * PSTR + qq] = __expf(s.z - cmv.z) * civ.z;
                Pt[(kk4 + 3) * PSTR + qq] = __expf(s.w - cmv.w) * civ.w;
            }
        }
        __syncthreads();
        #pragma unroll 2
        for (int kk = 0; kk < KC; ++kk) {
            float4 pa = *(const float4*)&Pt[kk * PSTR + r0];
            float4 pb = *(const float4*)&Pt[kk * PSTR + r0 + 4];
            float4 va = *(const float4*)&Vt[kk * DIM + c0];
            float4 vb = *(const float4*)&Vt[kk * DIM + c0 + 4];
            float p[8] = {pa.x, pa.y, pa.z, pa.w, pb.x, pb.y, pb.z, pb.w};
            float v[8] = {va.x, va.y, va.z, va.w, vb.x, vb.y, vb.z, vb.w};
            #pragma unroll
            for (int i = 0; i < 8; ++i)
                #pragma unroll
                for (int j = 0; j < 8; ++j)
                    acc[i][j] = fmaf(p[i], v[j], acc[i][j]);
        }
        __syncthreads();
    }

    float* dp = dst + (size_t)ks * ((size_t)NB * SEQ * DIM) + (size_t)b * SEQ * DIM;
    #pragma unroll
    for (int i = 0; i < 8; ++i) {
        float* o = dp + (size_t)(q0 + r0 + i) * DIM + c0;
        *(float4*)(o)     = make_float4(acc[i][0], acc[i][1], acc[i][2], acc[i][3]);
        *(float4*)(o + 4) = make_float4(acc[i][4], acc[i][5], acc[i][6], acc[i][7]);
    }
}

__global__ __launch_bounds__(256) void reduce_kernel(
    const float* __restrict__ part, float* __restrict__ out, int ksplit)
{
    int idx = blockIdx.x * 256 + threadIdx.x;
    const float4* p = (const float4*)part;
    float4 a = p[idx];
    for (int s = 1; s < ksplit; ++s) {
        float4 q = p[(size_t)idx + (size_t)s * 262144];
        a.x += q.x; a.y += q.y; a.z += q.z; a.w += q.w;
    }
    ((float4*)out)[idx] = a;
}

extern "C" void kernel_launch(void* const* d_in, const int* in_sizes, int n_in,
                              void* d_out, int out_size, void* d_ws, size_t ws_size,
                              hipStream_t stream)
{
    const float* queries = (const float*)d_in[0];
    const float* keys    = (const float*)d_in[1];
    const float* values  = (const float*)d_in[2];
    const int*   valid   = (const int*)d_in[3];
    const float* Wql = (const float*)d_in[4];
    const float* bql = (const float*)d_in[5];
    const float* Wkl = (const float*)d_in[6];
    const float* bkl = (const float*)d_in[7];
    const float* Wqh = (const float*)d_in[8];
    const float* bqh = (const float*)d_in[9];
    const float* Wkh = (const float*)d_in[10];
    const float* bkh = (const float*)d_in[11];

    char* ws = (char*)d_ws;
    float* Smat  = (float*)(ws);                       // 64 MB
    float* q_low = (float*)(ws + 67108864);            // 512 KB
    float* k_low = (float*)(ws + 67633152);            // 512 KB
    float* sh    = (float*)(ws + 68157440);            // 32 KB
    float* pm    = (float*)(ws + 68190208);            // 1 MB
    float* pl    = (float*)(ws + 69238784);            // 1 MB
    float* cmax  = (float*)(ws + 70287360);            // 32 KB
    float* cinv  = (float*)(ws + 70320128);            // 32 KB

    const size_t part_off = 73400320;                  // 70 MiB
    const size_t part_sz  = (size_t)NB * SEQ * DIM * 4;
    int ksplit = 1;
    if      (ws_size >= part_off + 8 * part_sz) ksplit = 8;
    else if (ws_size >= part_off + 4 * part_sz) ksplit = 4;
    else if (ws_size >= part_off + 2 * part_sz) ksplit = 2;
    float* part = (float*)(ws + part_off);

    proj_kernel<<<dim3((NB * SEQ) / 16), 256, 0, stream>>>(
        queries, keys, Wql, bql, Wkl, bkl, Wqh, bqh, Wkh, bkh, q_low, k_low, sh);

    score_topk5<<<dim3((NB * SEQ) / 8), 256, 0, stream>>>(
        q_low, k_low, sh, valid, Smat);

    colred_partial<<<dim3(SEQ / 256, 32, NB), 256, 0, stream>>>(Smat, pm, pl);

    colred_final<<<dim3((NB * SEQ) / 256), 256, 0, stream>>>(pm, pl, cmax, cinv);

    if (ksplit == 1) {
        out_kernel2<<<dim3(SEQ / QT, 1, NB), 256, 0, stream>>>(
            Smat, values, cmax, cinv, (float*)d_out, SEQ);
    } else {
        out_kernel2<<<dim3(SEQ / QT, ksplit, NB), 256, 0, stream>>>(
            Smat, values, cmax, cinv, part, SEQ / ksplit);
        reduce_kernel<<<(NB * SEQ * DIM / 4) / 256, 256, 0, stream>>>(
            part, (float*)d_out, ksplit);
    }
}

// Round 6
// 190.590 us; speedup vs baseline: 1.2789x; 1.1630x over previous
//
#include <hip/hip_runtime.h>
#include <float.h>
#include <math.h>

#define SEQ 2048
#define NB 4
#define DIM 128
#define DL 16
#define NEGV (-1e9f)
#define TOPK 8

#define QT 128      // q-rows per out block
#define KC 64       // k chunk staged in LDS (out kernel)
#define QCH 64      // q-chunk for colred

typedef unsigned long long u64;
typedef __attribute__((ext_vector_type(8))) short short8;
typedef __attribute__((ext_vector_type(4))) float f32x4;

__device__ __forceinline__ int lanes_below(u64 m) {
    return __builtin_amdgcn_mbcnt_hi((unsigned)(m >> 32),
           __builtin_amdgcn_mbcnt_lo((unsigned)m, 0));
}

__device__ __forceinline__ void top8_insert(float* s, float key) {
    #pragma unroll
    for (int i = 0; i < 8; ++i) {
        float a = s[i];
        s[i] = fmaxf(a, key);
        key  = fminf(a, key);
    }
}

__device__ __forceinline__ float top8_merge(float* s) {
    #pragma unroll
    for (int off = 1; off < 64; off <<= 1) {
        float o[8], t[8];
        #pragma unroll
        for (int i = 0; i < 8; ++i)
            o[i] = __shfl_xor(s[i], off, 64);
        #pragma unroll
        for (int i = 0; i < 8; ++i)
            t[i] = fmaxf(s[i], o[7 - i]);
        #pragma unroll
        for (int i = 0; i < 4; ++i) {
            float a = t[i], c = t[i + 4];
            t[i] = fmaxf(a, c); t[i + 4] = fminf(a, c);
        }
        #pragma unroll
        for (int g2 = 0; g2 < 8; g2 += 4) {
            float a = t[g2], c = t[g2 + 2];
            t[g2] = fmaxf(a, c); t[g2 + 2] = fminf(a, c);
            a = t[g2 + 1]; c = t[g2 + 3];
            t[g2 + 1] = fmaxf(a, c); t[g2 + 3] = fminf(a, c);
        }
        #pragma unroll
        for (int g1 = 0; g1 < 8; g1 += 2) {
            float a = t[g1], c = t[g1 + 1];
            t[g1] = fmaxf(a, c); t[g1 + 1] = fminf(a, c);
        }
        #pragma unroll
        for (int i = 0; i < 8; ++i) s[i] = t[i];
    }
    return s[7];
}

// bf16 round-to-nearest-even of f32 (returns 16-bit pattern)
__device__ __forceinline__ unsigned bf16_rne(float x) {
    unsigned u = __float_as_uint(x);
    return (u + 0x7FFFu + ((u >> 16) & 1u)) >> 16;
}

// ---------------------------------------------------------------------------
// Kernel A: q_low/k_low projections + per-key high-rank correction scalar sh.
// ---------------------------------------------------------------------------
__global__ __launch_bounds__(256) void proj_kernel(
    const float* __restrict__ q, const float* __restrict__ k,
    const float* __restrict__ Wql, const float* __restrict__ bql,
    const float* __restrict__ Wkl, const float* __restrict__ bkl,
    const float* __restrict__ Wqh, const float* __restrict__ bqh,
    const float* __restrict__ Wkh, const float* __restrict__ bkh,
    float* __restrict__ q_low, float* __restrict__ k_low,
    float* __restrict__ sh)
{
    __shared__ float Ws[4][DIM * DL];
    __shared__ float rowq[16][DIM];
    __shared__ float rowk[16][DIM];
    int tid = threadIdx.x;
    for (int i = tid; i < DIM * DL; i += 256) {
        Ws[0][i] = Wql[i];
        Ws[1][i] = Wkl[i];
        Ws[2][i] = Wqh[i];
        Ws[3][i] = Wkh[i];
    }
    int r0 = blockIdx.x * 16;
    for (int i = tid; i < 16 * DIM; i += 256) {
        int rr = i >> 7, cc = i & 127;
        rowq[rr][cc] = q[(size_t)(r0 + rr) * DIM + cc];
        rowk[rr][cc] = k[(size_t)(r0 + rr) * DIM + cc];
    }
    __syncthreads();
    int g = tid >> 4;
    int e = tid & 15;
    float aql = 0.f, akl = 0.f, aqh = 0.f, akh = 0.f;
    #pragma unroll 8
    for (int i = 0; i < DIM; ++i) {
        float qv = rowq[g][i], kv = rowk[g][i];
        aql = fmaf(qv, Ws[0][i * DL + e], aql);
        akl = fmaf(kv, Ws[1][i * DL + e], akl);
        aqh = fmaf(qv, Ws[2][i * DL + e], aqh);
        akh = fmaf(kv, Ws[3][i * DL + e], akh);
    }
    int t = r0 + g;
    q_low[(size_t)t * DL + e] = aql + bql[e];
    k_low[(size_t)t * DL + e] = akl + bkl[e];
    float qp = aqh + bqh[e];
    float kp = akh + bkh[e];
    float prod = qp * kp;
    #pragma unroll
    for (int off = 8; off >= 1; off >>= 1)
        prod += __shfl_xor(prod, off, 16);
    if (e == 0) sh[t] = 0.25f * prod;
}

// ---------------------------------------------------------------------------
// Kernel A2: V transpose + bf16 hi/lo split: VthH/VthL[b][d][k].
// ---------------------------------------------------------------------------
__global__ __launch_bounds__(256) void vsplit_kernel(
    const float* __restrict__ V, unsigned short* __restrict__ VH,
    unsigned short* __restrict__ VL)
{
    __shared__ float T[32][33];
    int kb = blockIdx.x * 32, db = blockIdx.y * 32, b = blockIdx.z;
    int tid = threadIdx.x;
    {
        int r = tid >> 3, cg = tid & 7;
        float4 v = *(const float4*)(V + ((size_t)b * SEQ + kb + r) * DIM + db + cg * 4);
        T[r][cg * 4 + 0] = v.x; T[r][cg * 4 + 1] = v.y;
        T[r][cg * 4 + 2] = v.z; T[r][cg * 4 + 3] = v.w;
    }
    __syncthreads();
    int dr = tid >> 3, kg = tid & 7;
    unsigned h[4], l[4];
    #pragma unroll
    for (int j = 0; j < 4; ++j) {
        float f = T[kg * 4 + j][dr];
        unsigned hi = bf16_rne(f);
        float hf = __uint_as_float(hi << 16);
        unsigned lo = bf16_rne(f - hf);
        h[j] = hi; l[j] = lo;
    }
    size_t o = ((size_t)b * DIM + db + dr) * SEQ + kb + kg * 4;
    *(uint2*)(VH + o) = make_uint2(h[0] | (h[1] << 16), h[2] | (h[3] << 16));
    *(uint2*)(VL + o) = make_uint2(l[0] | (l[1] << 16), l[2] | (l[3] << 16));
}

// ---------------------------------------------------------------------------
// Kernel B v5: block = 4 waves x 2 rows. k_low via 2-buffer LDS pipeline.
// Pass 1: scores -> Smat + value-only top-8. Pass 2: patch 8 winners with sh.
// ---------------------------------------------------------------------------
__global__ __launch_bounds__(256) void score_topk5(
    const float* __restrict__ q_low, const float* __restrict__ k_low,
    const float* __restrict__ sh, const int* __restrict__ valid_lens,
    float* __restrict__ Smat)
{
    __shared__ float KT[2][256 * DL];

    int tid  = threadIdx.x;
    int lane = tid & 63;
    int wv   = tid >> 6;
    int row0 = __builtin_amdgcn_readfirstlane(blockIdx.x * 8 + wv * 2);
    int b    = row0 >> 11;
    int qi0  = row0 & (SEQ - 1);
    int qi1  = qi0 + 1;

    float qv0[16], qv1[16];
    {
        const float* qp0 = q_low + (size_t)row0 * DL;
        #pragma unroll
        for (int e = 0; e < 16; ++e) { qv0[e] = qp0[e]; qv1[e] = qp0[DL + e]; }
    }

    const float4* kb4 = (const float4*)(k_low + (size_t)b * SEQ * DL);
    const int*    vlb = valid_lens + (size_t)b * SEQ;
    const float*  shb = sh + (size_t)b * SEQ;
    float* Srow0 = Smat + (size_t)row0 * SEQ;
    float* Srow1 = Srow0 + SEQ;

    float s0[8], s1[8];
    #pragma unroll
    for (int i = 0; i < 8; ++i) { s0[i] = -FLT_MAX; s1[i] = -FLT_MAX; }

    float4 stg[4];
    #pragma unroll
    for (int i = 0; i < 4; ++i) stg[i] = kb4[tid + i * 256];
    {
        float4* d = (float4*)KT[0];
        #pragma unroll
        for (int i = 0; i < 4; ++i) d[tid + i * 256] = stg[i];
    }
    __syncthreads();

    for (int c = 0; c < 8; ++c) {
        if (c < 7) {
            #pragma unroll
            for (int i = 0; i < 4; ++i)
                stg[i] = kb4[(c + 1) * 1024 + tid + i * 256];
        }
        int vli[4];
        #pragma unroll
        for (int j = 0; j < 4; ++j)
            vli[j] = vlb[c * 256 + lane + j * 64];

        const float* Kc = KT[c & 1];
        #pragma unroll
        for (int j = 0; j < 4; ++j) {
            int ccol = lane + j * 64;
            int col  = c * 256 + ccol;
            const float4* kp4 = (const float4*)(Kc + ccol * DL);
            float4 v0 = kp4[0], v1 = kp4[1], v2 = kp4[2], v3 = kp4[3];

            float a0 = 0.f, a1 = 0.f;
            a0 = fmaf(qv0[0],  v0.x, a0); a1 = fmaf(qv1[0],  v0.x, a1);
            a0 = fmaf(qv0[1],  v0.y, a0); a1 = fmaf(qv1[1],  v0.y, a1);
            a0 = fmaf(qv0[2],  v0.z, a0); a1 = fmaf(qv1[2],  v0.z, a1);
            a0 = fmaf(qv0[3],  v0.w, a0); a1 = fmaf(qv1[3],  v0.w, a1);
            a0 = fmaf(qv0[4],  v1.x, a0); a1 = fmaf(qv1[4],  v1.x, a1);
            a0 = fmaf(qv0[5],  v1.y, a0); a1 = fmaf(qv1[5],  v1.y, a1);
            a0 = fmaf(qv0[6],  v1.z, a0); a1 = fmaf(qv1[6],  v1.z, a1);
            a0 = fmaf(qv0[7],  v1.w, a0); a1 = fmaf(qv1[7],  v1.w, a1);
            a0 = fmaf(qv0[8],  v2.x, a0); a1 = fmaf(qv1[8],  v2.x, a1);
            a0 = fmaf(qv0[9],  v2.y, a0); a1 = fmaf(qv1[9],  v2.y, a1);
            a0 = fmaf(qv0[10], v2.z, a0); a1 = fmaf(qv1[10], v2.z, a1);
            a0 = fmaf(qv0[11], v2.w, a0); a1 = fmaf(qv1[11], v2.w, a1);
            a0 = fmaf(qv0[12], v3.x, a0); a1 = fmaf(qv1[12], v3.x, a1);
            a0 = fmaf(qv0[13], v3.y, a0); a1 = fmaf(qv1[13], v3.y, a1);
            a0 = fmaf(qv0[14], v3.z, a0); a1 = fmaf(qv1[14], v3.z, a1);
            a0 = fmaf(qv0[15], v3.w, a0); a1 = fmaf(qv1[15], v3.w, a1);
            a0 *= 0.25f; a1 *= 0.25f;

            int v = vli[j];
            v = v < 0 ? 0 : (v > SEQ - 1 ? SEQ - 1 : v);
            if (v == qi0) a0 += NEGV;
            if (v == qi1) a1 += NEGV;
            Srow0[col] = a0;
            Srow1[col] = a1;
            top8_insert(s0, a0);
            top8_insert(s1, a1);
        }
        if (c < 7) {
            float4* d = (float4*)KT[(c + 1) & 1];
            #pragma unroll
            for (int i = 0; i < 4; ++i) d[tid + i * 256] = stg[i];
            __syncthreads();
        }
    }

    float t8[2];
    t8[0] = top8_merge(s0);
    t8[1] = top8_merge(s1);

    for (int r = 0; r < 2; ++r) {
        float* Sr = r ? Srow1 : Srow0;
        float thr = t8[r];
        float sc[32];
        #pragma unroll 8
        for (int j = 0; j < 32; ++j)
            sc[j] = Sr[lane + j * 64];
        int cnt = 0;
        #pragma unroll
        for (int j = 0; j < 32; ++j) {
            cnt += (sc[j] >= thr) ? 1 : 0;
            cnt += (sc[j] >  thr) ? 65536 : 0;
        }
        #pragma unroll
        for (int off = 1; off < 64; off <<= 1)
            cnt += __shfl_xor(cnt, off, 64);
        int c_ge = cnt & 0xFFFF;
        int c_gt = cnt >> 16;

        if (c_ge == 8) {
            #pragma unroll 8
            for (int j = 0; j < 32; ++j) {
                int col = lane + j * 64;
                if (sc[j] >= thr) Sr[col] = shb[col];
            }
        } else {
            int need = 8 - c_gt;
            int total = 0;
            for (int j = 0; j < 32; ++j) {
                int col = lane + j * 64;
                bool eq = (sc[j] == thr);
                u64 bal = __ballot(eq);
                int before = total + lanes_below(bal);
                bool sel = (sc[j] > thr) || (eq && before < need);
                if (sel) Sr[col] = shb[col];
                total += (int)__popcll(bal);
            }
        }
    }
}

// ---------------------------------------------------------------------------
// Kernel C1/C2: column (q-axis) softmax stats.
// ---------------------------------------------------------------------------
__global__ __launch_bounds__(256) void colred_partial(
    const float* __restrict__ Smat, float* __restrict__ pm, float* __restrict__ pl)
{
    int kcol = blockIdx.x * 256 + threadIdx.x;
    int qc = blockIdx.y;
    int b  = blockIdx.z;
    const float* Sp = Smat + (size_t)b * SEQ * SEQ + (size_t)(qc * QCH) * SEQ + kcol;
    float m = -FLT_MAX, l = 0.f;
    #pragma unroll 4
    for (int qq = 0; qq < QCH; ++qq) {
        float v = Sp[(size_t)qq * SEQ];
        float nm = fmaxf(m, v);
        l = l * __expf(m - nm) + __expf(v - nm);
        m = nm;
    }
    pm[((size_t)b * 32 + qc) * SEQ + kcol] = m;
    pl[((size_t)b * 32 + qc) * SEQ + kcol] = l;
}

__global__ __launch_bounds__(256) void colred_final(
    const float* __restrict__ pm, const float* __restrict__ pl,
    float* __restrict__ cmax, float* __restrict__ cinv)
{
    int idx = blockIdx.x * 256 + threadIdx.x;
    int b = idx >> 11, kcol = idx & (SEQ - 1);
    float m = -FLT_MAX, l = 0.f;
    #pragma unroll
    for (int c = 0; c < 32; ++c) {
        float mm = pm[((size_t)b * 32 + c) * SEQ + kcol];
        float ll = pl[((size_t)b * 32 + c) * SEQ + kcol];
        float nm = fmaxf(m, mm);
        l = l * __expf(m - nm) + ll * __expf(mm - nm);
        m = nm;
    }
    cmax[idx] = m;
    cinv[idx] = 1.f / l;
}

// ---------------------------------------------------------------------------
// Kernel D v3: MFMA PV. Block = 128q x 128d, k-chunks of 64, ksplit partials.
// P A-fragments generated in registers from global S (hi/lo bf16 split);
// V^T hi/lo staged in XOR-swizzled LDS. out = PhVh + PlVh + PhVl.
// ---------------------------------------------------------------------------
__global__ __launch_bounds__(256) void out_mfma(
    const float* __restrict__ Smat, const unsigned short* __restrict__ VH,
    const unsigned short* __restrict__ VL,
    const float* __restrict__ cmax, const float* __restrict__ cinv,
    float* __restrict__ dst, int krange)
{
    __shared__ unsigned int VtH[DIM * 32];   // 16 KB, [d][k-words] XOR-swizzled
    __shared__ unsigned int VtL[DIM * 32];   // 16 KB

    int tid  = threadIdx.x;
    int w    = tid >> 6;
    int lane = tid & 63;
    int ln   = lane & 15;
    int quad = lane >> 4;
    int q0   = blockIdx.x * QT;
    int ksid = blockIdx.y;
    int b    = blockIdx.z;
    int kbeg = ksid * krange;

    const float* Sb = Smat + (size_t)b * SEQ * SEQ;
    const unsigned short* VHb = VH + (size_t)b * DIM * SEQ;
    const unsigned short* VLb = VL + (size_t)b * DIM * SEQ;
    const float* cm = cmax + (size_t)b * SEQ;
    const float* ci = cinv + (size_t)b * SEQ;

    f32x4 acc[2][8];
    #pragma unroll
    for (int mt = 0; mt < 2; ++mt)
        #pragma unroll
        for (int nt = 0; nt < 8; ++nt)
            acc[mt][nt] = (f32x4){0.f, 0.f, 0.f, 0.f};

    int sd0   = tid >> 3;   // staging d row (0..31, +32/iter)
    int skseg = tid & 7;    // staging k-segment (16B granule)

    for (int k0 = kbeg; k0 < kbeg + krange; k0 += KC) {
        // stage V^T hi/lo chunk [128d][64k] bf16, XOR-swizzled 16B granules
        #pragma unroll
        for (int it = 0; it < 4; ++it) {
            int d = sd0 + it * 32;
            size_t go = (size_t)d * SEQ + k0 + skseg * 8;
            uint4 hv = *(const uint4*)(VHb + go);
            uint4 lv = *(const uint4*)(VLb + go);
            int wa = d * 32 + ((skseg ^ (d & 7)) << 2);
            *(uint4*)&VtH[wa] = hv;
            *(uint4*)&VtL[wa] = lv;
        }

        // P A-fragments (registers): lane holds P[q=mtile+ln][k=quad*8+j]
        short8 Ah[2][2], Al[2][2];
        #pragma unroll
        for (int ks = 0; ks < 2; ++ks) {
            int kk = k0 + ks * 32 + quad * 8;
            float4 cma = *(const float4*)(cm + kk);
            float4 cmb = *(const float4*)(cm + kk + 4);
            float4 cia = *(const float4*)(ci + kk);
            float4 cib = *(const float4*)(ci + kk + 4);
            #pragma unroll
            for (int mt = 0; mt < 2; ++mt) {
                const float* Sp = Sb + (size_t)(q0 + w * 32 + mt * 16 + ln) * SEQ + kk;
                float4 sa = *(const float4*)Sp;
                float4 sb = *(const float4*)(Sp + 4);
                float p[8];
                p[0] = __expf(sa.x - cma.x) * cia.x;
                p[1] = __expf(sa.y - cma.y) * cia.y;
                p[2] = __expf(sa.z - cma.z) * cia.z;
                p[3] = __expf(sa.w - cma.w) * cia.w;
                p[4] = __expf(sb.x - cmb.x) * cib.x;
                p[5] = __expf(sb.y - cmb.y) * cib.y;
                p[6] = __expf(sb.z - cmb.z) * cib.z;
                p[7] = __expf(sb.w - cmb.w) * cib.w;
                #pragma unroll
                for (int j = 0; j < 8; ++j) {
                    unsigned hi = bf16_rne(p[j]);
                    float hf = __uint_as_float(hi << 16);
                    unsigned lo = bf16_rne(p[j] - hf);
                    Ah[mt][ks][j] = (short)hi;
                    Al[mt][ks][j] = (short)lo;
                }
            }
        }
        __syncthreads();

        #pragma unroll
        for (int nt = 0; nt < 8; ++nt) {
            int d = nt * 16 + ln;
            #pragma unroll
            for (int ks = 0; ks < 2; ++ks) {
                int kseg = ks * 4 + quad;
                int wa = d * 32 + ((kseg ^ (d & 7)) << 2);
                short8 bh = *(short8*)&VtH[wa];
                short8 bl = *(short8*)&VtL[wa];
                #pragma unroll
                for (int mt = 0; mt < 2; ++mt) {
                    acc[mt][nt] = __builtin_amdgcn_mfma_f32_16x16x32_bf16(
                        Ah[mt][ks], bh, acc[mt][nt], 0, 0, 0);
                    acc[mt][nt] = __builtin_amdgcn_mfma_f32_16x16x32_bf16(
                        Al[mt][ks], bh, acc[mt][nt], 0, 0, 0);
                    acc[mt][nt] = __builtin_amdgcn_mfma_f32_16x16x32_bf16(
                        Ah[mt][ks], bl, acc[mt][nt], 0, 0, 0);
                }
            }
        }
        __syncthreads();
    }

    float* dp = dst + (size_t)ksid * ((size_t)NB * SEQ * DIM)
                    + (size_t)b * SEQ * DIM;
    #pragma unroll
    for (int mt = 0; mt < 2; ++mt) {
        #pragma unroll
        for (int r = 0; r < 4; ++r) {
            float* o = dp + (size_t)(q0 + w * 32 + mt * 16 + quad * 4 + r) * DIM + ln;
            #pragma unroll
            for (int nt = 0; nt < 8; ++nt)
                o[nt * 16] = acc[mt][nt][r];
        }
    }
}

__global__ __launch_bounds__(256) void reduce_kernel(
    const float* __restrict__ part, float* __restrict__ out, int ksplit)
{
    int idx = blockIdx.x * 256 + threadIdx.x;
    const float4* p = (const float4*)part;
    float4 a = p[idx];
    for (int s = 1; s < ksplit; ++s) {
        float4 q = p[(size_t)idx + (size_t)s * 262144];
        a.x += q.x; a.y += q.y; a.z += q.z; a.w += q.w;
    }
    ((float4*)out)[idx] = a;
}

extern "C" void kernel_launch(void* const* d_in, const int* in_sizes, int n_in,
                              void* d_out, int out_size, void* d_ws, size_t ws_size,
                              hipStream_t stream)
{
    const float* queries = (const float*)d_in[0];
    const float* keys    = (const float*)d_in[1];
    const float* values  = (const float*)d_in[2];
    const int*   valid   = (const int*)d_in[3];
    const float* Wql = (const float*)d_in[4];
    const float* bql = (const float*)d_in[5];
    const float* Wkl = (const float*)d_in[6];
    const float* bkl = (const float*)d_in[7];
    const float* Wqh = (const float*)d_in[8];
    const float* bqh = (const float*)d_in[9];
    const float* Wkh = (const float*)d_in[10];
    const float* bkh = (const float*)d_in[11];

    char* ws = (char*)d_ws;
    float* Smat  = (float*)(ws);                        // 64 MB
    float* q_low = (float*)(ws + 67108864);             // 512 KB
    float* k_low = (float*)(ws + 67633152);             // 512 KB
    float* sh    = (float*)(ws + 68157440);             // 32 KB
    float* cmax  = (float*)(ws + 68190208);             // 32 KB
    float* cinv  = (float*)(ws + 68222976);             // 32 KB
    unsigned short* VthH = (unsigned short*)(ws + 68255744);  // 2 MB
    unsigned short* VthL = (unsigned short*)(ws + 70352896);  // 2 MB
    // pm/pl live only until colred_final; they overlap the part region,
    // which is written only afterwards (stream-ordered).
    float* pm    = (float*)(ws + 72450048);             // 1 MB
    float* pl    = (float*)(ws + 73498624);             // 1 MB
    float* part  = (float*)(ws + 72450048);             // ksplit*4 MB

    const size_t part_off = 72450048;
    const size_t part_sz  = (size_t)NB * SEQ * DIM * 4;  // 4 MB
    int ksplit = 1;
    if      (ws_size >= part_off + 8 * part_sz) ksplit = 8;
    else if (ws_size >= part_off + 4 * part_sz) ksplit = 4;
    else if (ws_size >= part_off + 2 * part_sz) ksplit = 2;

    proj_kernel<<<dim3((NB * SEQ) / 16), 256, 0, stream>>>(
        queries, keys, Wql, bql, Wkl, bkl, Wqh, bqh, Wkh, bkh, q_low, k_low, sh);

    vsplit_kernel<<<dim3(SEQ / 32, DIM / 32, NB), 256, 0, stream>>>(
        values, VthH, VthL);

    score_topk5<<<dim3((NB * SEQ) / 8), 256, 0, stream>>>(
        q_low, k_low, sh, valid, Smat);

    colred_partial<<<dim3(SEQ / 256, 32, NB), 256, 0, stream>>>(Smat, pm, pl);

    colred_final<<<dim3((NB * SEQ) / 256), 256, 0, stream>>>(pm, pl, cmax, cinv);

    if (ksplit == 1) {
        out_mfma<<<dim3(SEQ / QT, 1, NB), 256, 0, stream>>>(
            Smat, VthH, VthL, cmax, cinv, (float*)d_out, SEQ);
    } else {
        out_mfma<<<dim3(SEQ / QT, ksplit, NB), 256, 0, stream>>>(
            Smat, VthH, VthL, cmax, cinv, part, SEQ / ksplit);
        reduce_kernel<<<(NB * SEQ * DIM / 4) / 256, 256, 0, stream>>>(
            part, (float*)d_out, ksplit);
    }
}